// Round 5
// baseline (156.658 us; speedup 1.0000x reference)
//
#include <hip/hip_runtime.h>

// RoI bilinear crop-and-resize (TF2 half-pixel-center resize semantics).
// image: (1, 128, 128, 1024) f32, rois: (256, 4) f32 [x, y, w, h]
// out:   (1, 256, 14, 14, 1024) f32
//
// R5: image-band scheduling. Output pixels are binned by source row y0 into
// 8 bands of 16 image rows; band k's jobs are placed at blockIdx % 8 == k so
// each XCD's L2 streams one ~8MB band instead of 32 random ~1.8MB RoI
// footprints (L3/HBM read traffic ~460MB -> ~130MB). Main body = R3's
// per-pixel kernel (256 thr x float4 = 1024 ch) + NT stores.

#define H_ 128
#define W_ 128
#define C_ 1024
#define POOL_ 14
#define NROI_ 256
#define NPIX_ (NROI_ * POOL_ * POOL_)   // 50176
#define NRES_ 8
#define CAP_ 6800                        // per-band list capacity (avg 6272)

// ws layout (ints)
#define WS_CNT   0                       // [0..7] per-band counts
#define WS_OCNT  8                       // overflow count
#define WS_OCUR  9                       // overflow consume cursor (kernel B)
#define WS_LIST  16                      // [8][CAP_] band lists
#define WS_OLIST (WS_LIST + NRES_ * CAP_) // [NPIX_] overflow list

typedef float f32x4 __attribute__((ext_vector_type(4)));

__global__ __launch_bounds__(64) void zero_counters(int* __restrict__ ws) {
    if (threadIdx.x < WS_LIST) ws[threadIdx.x] = 0;
}

// One thread per output pixel: compute its source band (y0 >> 4), append.
__global__ __launch_bounds__(256) void bin_jobs(
    const float* __restrict__ rois, int* __restrict__ ws)
{
    const int j   = blockIdx.x * 256 + threadIdx.x;   // 0..NPIX_-1 exact grid
    const int n   = j / (POOL_ * POOL_);
    const int rem = j % (POOL_ * POOL_);
    const int yj  = rem / POOL_;

    const float y = rois[n * 4 + 1];
    const float h = rois[n * 4 + 3];
    const int c  = (int)rintf((y - h * 0.5f) / 16.0f);
    const int hf = max((int)rintf(h / 16.0f), 1);

    const float scy  = (float)hf / (float)POOL_;
    const float srcy = ((float)yj + 0.5f) * scy - 0.5f;
    const float fly  = floorf(srcy);
    int y0 = (int)fminf(fmaxf(fly, 0.0f), (float)(hf - 1)) + c;
    y0 = min(max(y0, 0), H_ - 1);

    const int r = y0 >> 4;                 // band 0..7
    const int lane = threadIdx.x & 63;

    // Wave-aggregated append: one atomic per (wave, band).
    int pos = -1;
    for (int rr = 0; rr < NRES_; ++rr) {
        unsigned long long m = __ballot(r == rr);
        if (m == 0ull) continue;
        int base = 0;
        const int leader = __ffsll((long long)m) - 1;
        if (lane == leader) base = atomicAdd(&ws[WS_CNT + rr], (int)__popcll(m));
        base = __shfl(base, leader);
        if (r == rr)
            pos = base + (int)__popcll(m & ((1ull << lane) - 1ull));
    }

    if (pos < CAP_) {
        ws[WS_LIST + r * CAP_ + pos] = j;
    } else {
        const int t = atomicAdd(&ws[WS_OCNT], 1);
        ws[WS_OLIST + t] = j;
    }
}

__global__ __launch_bounds__(256) void roi_pool_kernel(
    const float* __restrict__ feat,   // (H, W, C)
    const float* __restrict__ rois,   // (N, 4)
    float* __restrict__ out,          // (N, 14, 14, C)
    int* __restrict__ ws)
{
    __shared__ int s_j;
    if (threadIdx.x == 0) {
        const int r = blockIdx.x % NRES_;      // residue -> XCD
        const int s = blockIdx.x / NRES_;
        const int cnt = min(ws[WS_CNT + r], CAP_);
        int j;
        if (s < cnt) {
            j = ws[WS_LIST + r * CAP_ + s];
        } else {
            const int t  = atomicAdd(&ws[WS_OCUR], 1);
            const int on = ws[WS_OCNT];
            j = (t < on) ? ws[WS_OLIST + t] : -1;
        }
        s_j = j;
    }
    __syncthreads();
    const int blk = s_j;
    if (blk < 0) return;

    const int xj = blk % POOL_;
    const int yj = (blk / POOL_) % POOL_;
    const int n  = blk / (POOL_ * POOL_);

    const float x = rois[n * 4 + 0];
    const float y = rois[n * 4 + 1];
    const float w = rois[n * 4 + 2];
    const float h = rois[n * 4 + 3];

    // jnp.round == round-half-to-even == rintf
    const int r  = (int)rintf((x - w * 0.5f) / 16.0f);
    const int c  = (int)rintf((y - h * 0.5f) / 16.0f);
    const int wf = max((int)rintf(w / 16.0f), 1);
    const int hf = max((int)rintf(h / 16.0f), 1);

    // y axis (rows): start=c, size=hf, limit=H
    const float scy  = (float)hf / (float)POOL_;
    const float srcy = ((float)yj + 0.5f) * scy - 0.5f;
    const float fly  = floorf(srcy);
    const float ty   = srcy - fly;                 // unclamped lerp weight
    const float hiy  = (float)(hf - 1);
    int y0 = (int)fminf(fmaxf(fly, 0.0f), hiy) + c;
    int y1 = (int)fminf(fmaxf(fly + 1.0f, 0.0f), hiy) + c;
    y0 = min(max(y0, 0), H_ - 1);
    y1 = min(max(y1, 0), H_ - 1);

    // x axis (cols): start=r, size=wf, limit=W
    const float scx  = (float)wf / (float)POOL_;
    const float srcx = ((float)xj + 0.5f) * scx - 0.5f;
    const float flx  = floorf(srcx);
    const float tx   = srcx - flx;
    const float hix  = (float)(wf - 1);
    int x0 = (int)fminf(fmaxf(flx, 0.0f), hix) + r;
    int x1 = (int)fminf(fmaxf(flx + 1.0f, 0.0f), hix) + r;
    x0 = min(max(x0, 0), W_ - 1);
    x1 = min(max(x1, 0), W_ - 1);

    const f32x4* __restrict__ p00 = (const f32x4*)(feat + ((size_t)y0 * W_ + x0) * C_);
    const f32x4* __restrict__ p01 = (const f32x4*)(feat + ((size_t)y0 * W_ + x1) * C_);
    const f32x4* __restrict__ p10 = (const f32x4*)(feat + ((size_t)y1 * W_ + x0) * C_);
    const f32x4* __restrict__ p11 = (const f32x4*)(feat + ((size_t)y1 * W_ + x1) * C_);
    f32x4* __restrict__ po = (f32x4*)(out + (size_t)blk * C_);

    const int tid = threadIdx.x;   // 0..255, C/4 = 256 float4 per pixel

    const f32x4 v00 = p00[tid];
    const f32x4 v01 = p01[tid];
    const f32x4 v10 = p10[tid];
    const f32x4 v11 = p11[tid];

    const float omty = 1.0f - ty;
    const float omtx = 1.0f - tx;

    // Match reference order: (v00*(1-ty) + v10*ty)*(1-tx) + (v01*(1-ty) + v11*ty)*tx
    f32x4 o = (v00 * omty + v10 * ty) * omtx + (v01 * omty + v11 * ty) * tx;

    // Non-temporal: stream the output past L2/L3 so the image stays cached.
    __builtin_nontemporal_store(o, &po[tid]);
}

extern "C" void kernel_launch(void* const* d_in, const int* in_sizes, int n_in,
                              void* d_out, int out_size, void* d_ws, size_t ws_size,
                              hipStream_t stream) {
    const float* feat = (const float*)d_in[0];   // (1,128,128,1024) f32
    const float* rois = (const float*)d_in[1];   // (256,4) f32
    float* out = (float*)d_out;                  // (1,256,14,14,1024) f32
    int* ws = (int*)d_ws;

    zero_counters<<<1, 64, 0, stream>>>(ws);
    bin_jobs<<<NPIX_ / 256, 256, 0, stream>>>(rois, ws);
    roi_pool_kernel<<<NRES_ * CAP_, 256, 0, stream>>>(feat, rois, out, ws);
}

// Round 6
// 93.384 us; speedup vs baseline: 1.6776x; 1.6776x over previous
//
#include <hip/hip_runtime.h>

// RoI bilinear crop-and-resize (TF2 half-pixel-center resize semantics).
// image: (1, 128, 128, 1024) f32, rois: (256, 4) f32 [x, y, w, h]
// out:   (1, 256, 14, 14, 1024) f32
//
// R6: deterministic image-band scheduling (fixes R5's 3 defects: overflow
// tail, scrambled order, nondeterminism). Counting sort of the 50176 output
// pixels into 8 bands of 16 source rows, exact ascending-j order per band
// (atomic-free: count -> prefix -> ballot-rank scatter). Main kernel pins
// band k to XCD k (blockIdx = s*8 + k) and consumes in j order, so each
// XCD's L2 sees an RoI-clustered ~4MB window. Body = R3 kernel + NT stores.

#define H_ 128
#define W_ 128
#define C_ 1024
#define POOL_ 14
#define NROI_ 256
#define NPIX_ (NROI_ * POOL_ * POOL_)   // 50176
#define NBIN_ (NPIX_ / 256)             // 196 binner blocks
#define NB_ 8                            // bands of 16 source rows
#define CAPB_ 10240                      // per-band capacity (expected max ~7.2K)

// ws layout (ints)
#define WS_CNT  0                        // [8] band totals
#define WS_BO   16                       // [196][8] counts -> exclusive offsets
#define WS_LIST (16 + NBIN_ * NB_)       // [8][CAPB_] sorted job lists
#define WS_INTS (WS_LIST + NB_ * CAPB_)

typedef float f32x4 __attribute__((ext_vector_type(4)));

__device__ __forceinline__ int src_y0(const float* __restrict__ rois, int j) {
    const int n  = j / (POOL_ * POOL_);
    const int yj = (j / POOL_) % POOL_;
    const float y = rois[n * 4 + 1];
    const float h = rois[n * 4 + 3];
    const int c  = (int)rintf((y - h * 0.5f) / 16.0f);
    const int hf = max((int)rintf(h / 16.0f), 1);
    const float scy  = (float)hf / (float)POOL_;
    const float srcy = ((float)yj + 0.5f) * scy - 0.5f;
    const float fly  = floorf(srcy);
    int y0 = (int)fminf(fmaxf(fly, 0.0f), (float)(hf - 1)) + c;
    return min(max(y0, 0), H_ - 1);
}

// B: per-block per-band counts (LDS atomics only; order-independent).
__global__ __launch_bounds__(256) void count_bands(
    const float* __restrict__ rois, int* __restrict__ ws)
{
    __shared__ int scnt[NB_];
    if (threadIdx.x < NB_) scnt[threadIdx.x] = 0;
    __syncthreads();
    const int j = blockIdx.x * 256 + threadIdx.x;      // exact: NBIN_*256 == NPIX_
    const int b = src_y0(rois, j) >> 4;
    atomicAdd(&scnt[b], 1);
    __syncthreads();
    if (threadIdx.x < NB_)
        ws[WS_BO + blockIdx.x * NB_ + threadIdx.x] = scnt[threadIdx.x];
}

// C: hierarchical exclusive prefix over [196][8] (in place) + band totals.
__global__ __launch_bounds__(64) void prefix_bands(int* __restrict__ ws)
{
    __shared__ int p[8][NB_];
    const int b = threadIdx.x & 7;
    const int cidx = threadIdx.x >> 3;                 // 8 chunks of 25 blocks
    const int k0 = cidx * 25, k1 = min(NBIN_, k0 + 25);
    int s = 0;
    #pragma unroll
    for (int k = k0; k < k1; ++k) s += ws[WS_BO + k * NB_ + b];
    p[cidx][b] = s;
    __syncthreads();
    if (cidx == 0) {
        int run = 0;
        #pragma unroll
        for (int cc = 0; cc < 8; ++cc) { int t = p[cc][b]; p[cc][b] = run; run += t; }
        ws[WS_CNT + b] = run;                          // band total
    }
    __syncthreads();
    int run = p[cidx][b];
    for (int k = k0; k < k1; ++k) {
        int t = ws[WS_BO + k * NB_ + b];
        ws[WS_BO + k * NB_ + b] = run;                 // exclusive offset
        run += t;
    }
}

// D: deterministic scatter — ballot-rank within block, j ascending per band.
__global__ __launch_bounds__(256) void scatter_jobs(
    const float* __restrict__ rois, int* __restrict__ ws)
{
    __shared__ int wcnt[4][NB_];
    const int j = blockIdx.x * 256 + threadIdx.x;
    const int b = src_y0(rois, j) >> 4;
    const int wave = threadIdx.x >> 6, lane = threadIdx.x & 63;
    int myrank = 0;
    #pragma unroll
    for (int bb = 0; bb < NB_; ++bb) {
        unsigned long long m = __ballot(b == bb);
        if (b == bb) myrank = (int)__popcll(m & ((1ull << lane) - 1ull));
        if (lane == bb) wcnt[wave][bb] = (int)__popcll(m);
    }
    __syncthreads();
    int off = ws[WS_BO + blockIdx.x * NB_ + b];
    #pragma unroll
    for (int w = 0; w < 4; ++w) if (w < wave) off += wcnt[w][b];
    const int pos = off + myrank;
    if (pos < CAPB_) ws[WS_LIST + b * CAPB_ + pos] = j;   // guard (never expected)
}

// E: main — band k pinned to XCD k, consumed in ascending-j order.
__global__ __launch_bounds__(256) void roi_pool_banded(
    const float* __restrict__ feat, const float* __restrict__ rois,
    float* __restrict__ out, const int* __restrict__ ws)
{
    const int r = blockIdx.x & 7;                      // band == XCD (blockIdx%8)
    const int s = blockIdx.x >> 3;
    const int cnt = min(ws[WS_CNT + r], CAPB_);
    if (s >= cnt) return;
    const int blk = ws[WS_LIST + r * CAPB_ + s];       // wave-uniform scalar load

    const int xj = blk % POOL_;
    const int yj = (blk / POOL_) % POOL_;
    const int n  = blk / (POOL_ * POOL_);

    const float x = rois[n * 4 + 0];
    const float y = rois[n * 4 + 1];
    const float w = rois[n * 4 + 2];
    const float h = rois[n * 4 + 3];

    // jnp.round == round-half-to-even == rintf
    const int r_  = (int)rintf((x - w * 0.5f) / 16.0f);
    const int c_  = (int)rintf((y - h * 0.5f) / 16.0f);
    const int wf = max((int)rintf(w / 16.0f), 1);
    const int hf = max((int)rintf(h / 16.0f), 1);

    // y axis
    const float scy  = (float)hf / (float)POOL_;
    const float srcy = ((float)yj + 0.5f) * scy - 0.5f;
    const float fly  = floorf(srcy);
    const float ty   = srcy - fly;
    const float hiy  = (float)(hf - 1);
    int y0 = (int)fminf(fmaxf(fly, 0.0f), hiy) + c_;
    int y1 = (int)fminf(fmaxf(fly + 1.0f, 0.0f), hiy) + c_;
    y0 = min(max(y0, 0), H_ - 1);
    y1 = min(max(y1, 0), H_ - 1);

    // x axis
    const float scx  = (float)wf / (float)POOL_;
    const float srcx = ((float)xj + 0.5f) * scx - 0.5f;
    const float flx  = floorf(srcx);
    const float tx   = srcx - flx;
    const float hix  = (float)(wf - 1);
    int x0 = (int)fminf(fmaxf(flx, 0.0f), hix) + r_;
    int x1 = (int)fminf(fmaxf(flx + 1.0f, 0.0f), hix) + r_;
    x0 = min(max(x0, 0), W_ - 1);
    x1 = min(max(x1, 0), W_ - 1);

    const f32x4* __restrict__ p00 = (const f32x4*)(feat + ((size_t)y0 * W_ + x0) * C_);
    const f32x4* __restrict__ p01 = (const f32x4*)(feat + ((size_t)y0 * W_ + x1) * C_);
    const f32x4* __restrict__ p10 = (const f32x4*)(feat + ((size_t)y1 * W_ + x0) * C_);
    const f32x4* __restrict__ p11 = (const f32x4*)(feat + ((size_t)y1 * W_ + x1) * C_);
    f32x4* __restrict__ po = (f32x4*)(out + (size_t)blk * C_);

    const int tid = threadIdx.x;

    const f32x4 v00 = p00[tid];
    const f32x4 v01 = p01[tid];
    const f32x4 v10 = p10[tid];
    const f32x4 v11 = p11[tid];

    const float omty = 1.0f - ty;
    const float omtx = 1.0f - tx;

    // Match reference order: (v00*(1-ty) + v10*ty)*(1-tx) + (v01*(1-ty) + v11*ty)*tx
    f32x4 o = (v00 * omty + v10 * ty) * omtx + (v01 * omty + v11 * ty) * tx;

    __builtin_nontemporal_store(o, &po[tid]);
}

// Fallback (ws too small): R3's proven direct kernel + XCD swizzle.
__global__ __launch_bounds__(256) void roi_pool_direct(
    const float* __restrict__ feat, const float* __restrict__ rois,
    float* __restrict__ out)
{
    const int bid = blockIdx.x;
    const int blk = (bid % 8) * (NPIX_ / 8) + bid / 8;

    const int xj = blk % POOL_;
    const int yj = (blk / POOL_) % POOL_;
    const int n  = blk / (POOL_ * POOL_);

    const float x = rois[n * 4 + 0];
    const float y = rois[n * 4 + 1];
    const float w = rois[n * 4 + 2];
    const float h = rois[n * 4 + 3];

    const int r_  = (int)rintf((x - w * 0.5f) / 16.0f);
    const int c_  = (int)rintf((y - h * 0.5f) / 16.0f);
    const int wf = max((int)rintf(w / 16.0f), 1);
    const int hf = max((int)rintf(h / 16.0f), 1);

    const float scy  = (float)hf / (float)POOL_;
    const float srcy = ((float)yj + 0.5f) * scy - 0.5f;
    const float fly  = floorf(srcy);
    const float ty   = srcy - fly;
    const float hiy  = (float)(hf - 1);
    int y0 = (int)fminf(fmaxf(fly, 0.0f), hiy) + c_;
    int y1 = (int)fminf(fmaxf(fly + 1.0f, 0.0f), hiy) + c_;
    y0 = min(max(y0, 0), H_ - 1);
    y1 = min(max(y1, 0), H_ - 1);

    const float scx  = (float)wf / (float)POOL_;
    const float srcx = ((float)xj + 0.5f) * scx - 0.5f;
    const float flx  = floorf(srcx);
    const float tx   = srcx - flx;
    const float hix  = (float)(wf - 1);
    int x0 = (int)fminf(fmaxf(flx, 0.0f), hix) + r_;
    int x1 = (int)fminf(fmaxf(flx + 1.0f, 0.0f), hix) + r_;
    x0 = min(max(x0, 0), W_ - 1);
    x1 = min(max(x1, 0), W_ - 1);

    const f32x4* __restrict__ p00 = (const f32x4*)(feat + ((size_t)y0 * W_ + x0) * C_);
    const f32x4* __restrict__ p01 = (const f32x4*)(feat + ((size_t)y0 * W_ + x1) * C_);
    const f32x4* __restrict__ p10 = (const f32x4*)(feat + ((size_t)y1 * W_ + x0) * C_);
    const f32x4* __restrict__ p11 = (const f32x4*)(feat + ((size_t)y1 * W_ + x1) * C_);
    f32x4* __restrict__ po = (f32x4*)(out + (size_t)blk * C_);

    const int tid = threadIdx.x;
    const f32x4 v00 = p00[tid];
    const f32x4 v01 = p01[tid];
    const f32x4 v10 = p10[tid];
    const f32x4 v11 = p11[tid];

    const float omty = 1.0f - ty;
    const float omtx = 1.0f - tx;
    f32x4 o = (v00 * omty + v10 * ty) * omtx + (v01 * omty + v11 * ty) * tx;
    __builtin_nontemporal_store(o, &po[tid]);
}

extern "C" void kernel_launch(void* const* d_in, const int* in_sizes, int n_in,
                              void* d_out, int out_size, void* d_ws, size_t ws_size,
                              hipStream_t stream) {
    const float* feat = (const float*)d_in[0];   // (1,128,128,1024) f32
    const float* rois = (const float*)d_in[1];   // (256,4) f32
    float* out = (float*)d_out;                  // (1,256,14,14,1024) f32

    if (ws_size < (size_t)WS_INTS * sizeof(int)) {
        roi_pool_direct<<<NPIX_, 256, 0, stream>>>(feat, rois, out);
        return;
    }

    int* ws = (int*)d_ws;
    count_bands<<<NBIN_, 256, 0, stream>>>(rois, ws);
    prefix_bands<<<1, 64, 0, stream>>>(ws);
    scatter_jobs<<<NBIN_, 256, 0, stream>>>(rois, ws);
    roi_pool_banded<<<NB_ * CAPB_, 256, 0, stream>>>(feat, rois, out, ws);
}

// Round 7
// 76.645 us; speedup vs baseline: 2.0439x; 1.2184x over previous
//
#include <hip/hip_runtime.h>

// RoI bilinear crop-and-resize (TF2 half-pixel-center resize semantics).
// image: (1, 128, 128, 1024) f32, rois: (256, 4) f32 [x, y, w, h]
// out:   (1, 256, 14, 14, 1024) f32
//
// R7: full counting sort of the 50176 output-pixel jobs by SOURCE ROW y0
// (128 bins) -> sorted permutation list -> 8 equal contiguous chunks, chunk k
// pinned to XCD k (blockIdx%8). Each XCD's L2 then streams ~16 image rows
// monotonically (working set ~1MB per y0-run), collapsing L2-miss/fabric
// read volume from ~450MB (RoI-major order, R3/R6) to ~one image pass.
// R6's banding failed only because its within-band order was RoI-major.
// Main body = R3 per-pixel kernel (256 thr x f32x4 = 1024 ch) + NT stores.

#define H_ 128
#define W_ 128
#define C_ 1024
#define POOL_ 14
#define NROI_ 256
#define NPIX_ (NROI_ * POOL_ * POOL_)   // 50176
#define NBIN_ (NPIX_ / 256)             // 196 binner blocks
#define NBINS_ 128                       // one bin per source row y0
#define CHUNK_ (NPIX_ / 8)               // 6272 jobs per XCD

// ws layout (ints)
#define WS_BO   0                        // [196][128] counts -> global excl offsets
#define WS_LIST (NBIN_ * NBINS_)         // [NPIX_] sorted job list (permutation)
#define WS_INTS (WS_LIST + NPIX_)        // 75264 ints = 301 KB

typedef float f32x4 __attribute__((ext_vector_type(4)));

__device__ __forceinline__ int src_y0(const float* __restrict__ rois, int j) {
    const int n  = j / (POOL_ * POOL_);
    const int yj = (j / POOL_) % POOL_;
    const float y = rois[n * 4 + 1];
    const float h = rois[n * 4 + 3];
    const int c  = (int)rintf((y - h * 0.5f) / 16.0f);
    const int hf = max((int)rintf(h / 16.0f), 1);
    const float scy  = (float)hf / (float)POOL_;
    const float srcy = ((float)yj + 0.5f) * scy - 0.5f;
    const float fly  = floorf(srcy);
    int y0 = (int)fminf(fmaxf(fly, 0.0f), (float)(hf - 1)) + c;
    return min(max(y0, 0), H_ - 1);
}

// A: per-block y0 histogram (LDS atomics; order-independent).
__global__ __launch_bounds__(256) void count_y0(
    const float* __restrict__ rois, int* __restrict__ ws)
{
    __shared__ int hist[NBINS_];
    if (threadIdx.x < NBINS_) hist[threadIdx.x] = 0;
    __syncthreads();
    const int j = blockIdx.x * 256 + threadIdx.x;      // exact: NBIN_*256 == NPIX_
    atomicAdd(&hist[src_y0(rois, j)], 1);
    __syncthreads();
    if (threadIdx.x < NBINS_)
        ws[WS_BO + blockIdx.x * NBINS_ + threadIdx.x] = hist[threadIdx.x];
}

// B: global exclusive offsets: off(k,b) = sum_{b'<b} total[b'] + sum_{k'<k} cnt[k'][b].
__global__ __launch_bounds__(128) void prefix_y0(int* __restrict__ ws)
{
    __shared__ int tot[NBINS_];
    const int b = threadIdx.x;                         // one bin per thread
    int run = 0;
    for (int k = 0; k < NBIN_; ++k) {                  // within-bin exclusive scan
        const int t = ws[WS_BO + k * NBINS_ + b];
        ws[WS_BO + k * NBINS_ + b] = run;
        run += t;
    }
    tot[b] = run;
    __syncthreads();
    if (b == 0) {                                      // exclusive scan over bins
        int r = 0;
        for (int i = 0; i < NBINS_; ++i) { const int t = tot[i]; tot[i] = r; r += t; }
    }
    __syncthreads();
    const int base = tot[b];
    for (int k = 0; k < NBIN_; ++k)
        ws[WS_BO + k * NBINS_ + b] += base;
}

// C: scatter jobs to sorted list. Rank within (block,bin) via LDS atomic —
// intra-bin order is irrelevant (locality only); output stays deterministic
// since every job writes its own disjoint 4KB of d_out.
__global__ __launch_bounds__(256) void scatter_y0(
    const float* __restrict__ rois, int* __restrict__ ws)
{
    __shared__ int hist[NBINS_];
    if (threadIdx.x < NBINS_) hist[threadIdx.x] = 0;
    __syncthreads();
    const int j = blockIdx.x * 256 + threadIdx.x;
    const int b = src_y0(rois, j);
    const int r = atomicAdd(&hist[b], 1);
    const int pos = ws[WS_BO + blockIdx.x * NBINS_ + b] + r;
    ws[WS_LIST + pos] = j;
}

// D: main — sorted list split into 8 contiguous chunks, chunk k on XCD k.
__global__ __launch_bounds__(256) void roi_pool_sorted(
    const float* __restrict__ feat, const float* __restrict__ rois,
    float* __restrict__ out, const int* __restrict__ ws)
{
    const int s = (blockIdx.x & 7) * CHUNK_ + (blockIdx.x >> 3);
    const int blk = ws[WS_LIST + s];                   // wave-uniform scalar load

    const int xj = blk % POOL_;
    const int yj = (blk / POOL_) % POOL_;
    const int n  = blk / (POOL_ * POOL_);

    const float x = rois[n * 4 + 0];
    const float y = rois[n * 4 + 1];
    const float w = rois[n * 4 + 2];
    const float h = rois[n * 4 + 3];

    // jnp.round == round-half-to-even == rintf
    const int r_  = (int)rintf((x - w * 0.5f) / 16.0f);
    const int c_  = (int)rintf((y - h * 0.5f) / 16.0f);
    const int wf = max((int)rintf(w / 16.0f), 1);
    const int hf = max((int)rintf(h / 16.0f), 1);

    // y axis
    const float scy  = (float)hf / (float)POOL_;
    const float srcy = ((float)yj + 0.5f) * scy - 0.5f;
    const float fly  = floorf(srcy);
    const float ty   = srcy - fly;
    const float hiy  = (float)(hf - 1);
    int y0 = (int)fminf(fmaxf(fly, 0.0f), hiy) + c_;
    int y1 = (int)fminf(fmaxf(fly + 1.0f, 0.0f), hiy) + c_;
    y0 = min(max(y0, 0), H_ - 1);
    y1 = min(max(y1, 0), H_ - 1);

    // x axis
    const float scx  = (float)wf / (float)POOL_;
    const float srcx = ((float)xj + 0.5f) * scx - 0.5f;
    const float flx  = floorf(srcx);
    const float tx   = srcx - flx;
    const float hix  = (float)(wf - 1);
    int x0 = (int)fminf(fmaxf(flx, 0.0f), hix) + r_;
    int x1 = (int)fminf(fmaxf(flx + 1.0f, 0.0f), hix) + r_;
    x0 = min(max(x0, 0), W_ - 1);
    x1 = min(max(x1, 0), W_ - 1);

    const f32x4* __restrict__ p00 = (const f32x4*)(feat + ((size_t)y0 * W_ + x0) * C_);
    const f32x4* __restrict__ p01 = (const f32x4*)(feat + ((size_t)y0 * W_ + x1) * C_);
    const f32x4* __restrict__ p10 = (const f32x4*)(feat + ((size_t)y1 * W_ + x0) * C_);
    const f32x4* __restrict__ p11 = (const f32x4*)(feat + ((size_t)y1 * W_ + x1) * C_);
    f32x4* __restrict__ po = (f32x4*)(out + (size_t)blk * C_);

    const int tid = threadIdx.x;

    const f32x4 v00 = p00[tid];
    const f32x4 v01 = p01[tid];
    const f32x4 v10 = p10[tid];
    const f32x4 v11 = p11[tid];

    const float omty = 1.0f - ty;
    const float omtx = 1.0f - tx;

    // Match reference order: (v00*(1-ty) + v10*ty)*(1-tx) + (v01*(1-ty) + v11*ty)*tx
    f32x4 o = (v00 * omty + v10 * ty) * omtx + (v01 * omty + v11 * ty) * tx;

    __builtin_nontemporal_store(o, &po[tid]);
}

// Fallback (ws too small): R3's proven direct kernel + XCD swizzle.
__global__ __launch_bounds__(256) void roi_pool_direct(
    const float* __restrict__ feat, const float* __restrict__ rois,
    float* __restrict__ out)
{
    const int bid = blockIdx.x;
    const int blk = (bid % 8) * (NPIX_ / 8) + bid / 8;

    const int xj = blk % POOL_;
    const int yj = (blk / POOL_) % POOL_;
    const int n  = blk / (POOL_ * POOL_);

    const float x = rois[n * 4 + 0];
    const float y = rois[n * 4 + 1];
    const float w = rois[n * 4 + 2];
    const float h = rois[n * 4 + 3];

    const int r_  = (int)rintf((x - w * 0.5f) / 16.0f);
    const int c_  = (int)rintf((y - h * 0.5f) / 16.0f);
    const int wf = max((int)rintf(w / 16.0f), 1);
    const int hf = max((int)rintf(h / 16.0f), 1);

    const float scy  = (float)hf / (float)POOL_;
    const float srcy = ((float)yj + 0.5f) * scy - 0.5f;
    const float fly  = floorf(srcy);
    const float ty   = srcy - fly;
    const float hiy  = (float)(hf - 1);
    int y0 = (int)fminf(fmaxf(fly, 0.0f), hiy) + c_;
    int y1 = (int)fminf(fmaxf(fly + 1.0f, 0.0f), hiy) + c_;
    y0 = min(max(y0, 0), H_ - 1);
    y1 = min(max(y1, 0), H_ - 1);

    const float scx  = (float)wf / (float)POOL_;
    const float srcx = ((float)xj + 0.5f) * scx - 0.5f;
    const float flx  = floorf(srcx);
    const float tx   = srcx - flx;
    const float hix  = (float)(wf - 1);
    int x0 = (int)fminf(fmaxf(flx, 0.0f), hix) + r_;
    int x1 = (int)fminf(fmaxf(flx + 1.0f, 0.0f), hix) + r_;
    x0 = min(max(x0, 0), W_ - 1);
    x1 = min(max(x1, 0), W_ - 1);

    const f32x4* __restrict__ p00 = (const f32x4*)(feat + ((size_t)y0 * W_ + x0) * C_);
    const f32x4* __restrict__ p01 = (const f32x4*)(feat + ((size_t)y0 * W_ + x1) * C_);
    const f32x4* __restrict__ p10 = (const f32x4*)(feat + ((size_t)y1 * W_ + x0) * C_);
    const f32x4* __restrict__ p11 = (const f32x4*)(feat + ((size_t)y1 * W_ + x1) * C_);
    f32x4* __restrict__ po = (f32x4*)(out + (size_t)blk * C_);

    const int tid = threadIdx.x;
    const f32x4 v00 = p00[tid];
    const f32x4 v01 = p01[tid];
    const f32x4 v10 = p10[tid];
    const f32x4 v11 = p11[tid];

    const float omty = 1.0f - ty;
    const float omtx = 1.0f - tx;
    f32x4 o = (v00 * omty + v10 * ty) * omtx + (v01 * omty + v11 * ty) * tx;
    __builtin_nontemporal_store(o, &po[tid]);
}

extern "C" void kernel_launch(void* const* d_in, const int* in_sizes, int n_in,
                              void* d_out, int out_size, void* d_ws, size_t ws_size,
                              hipStream_t stream) {
    const float* feat = (const float*)d_in[0];   // (1,128,128,1024) f32
    const float* rois = (const float*)d_in[1];   // (256,4) f32
    float* out = (float*)d_out;                  // (1,256,14,14,1024) f32

    if (ws_size < (size_t)WS_INTS * sizeof(int)) {
        roi_pool_direct<<<NPIX_, 256, 0, stream>>>(feat, rois, out);
        return;
    }

    int* ws = (int*)d_ws;
    count_y0<<<NBIN_, 256, 0, stream>>>(rois, ws);
    prefix_y0<<<1, 128, 0, stream>>>(ws);
    scatter_y0<<<NBIN_, 256, 0, stream>>>(rois, ws);
    roi_pool_sorted<<<NPIX_, 256, 0, stream>>>(feat, rois, out, ws);
}

// Round 8
// 61.597 us; speedup vs baseline: 2.5433x; 1.2443x over previous
//
#include <hip/hip_runtime.h>

// RoI bilinear crop-and-resize (TF2 half-pixel-center resize semantics).
// image: (1, 128, 128, 1024) f32, rois: (256, 4) f32 [x, y, w, h]
// out:   (1, 256, 14, 14, 1024) f32
//
// R8: y0-sorted scheduling (R7, which gave 85.6->76.6us) with the 3-kernel
// 50K-job counting sort replaced by ONE tiny single-block kernel sorting the
// 3584 output ROWS (n,yj) by source row y0 (all 14 xj share y0). Bonus: the
// 14 pixels of a row become consecutive jobs -> adjacent blocks share the
// x-window (L1/L2 hits). Main kernel: XCD k consumes the k-th contiguous
// chunk of the sorted job order (blockIdx%8 -> XCD). Body = R3 per-pixel
// kernel (256 thr x f32x4 = 1024 ch) + NT stores.

#define H_ 128
#define W_ 128
#define C_ 1024
#define POOL_ 14
#define NROI_ 256
#define NPIX_ (NROI_ * POOL_ * POOL_)   // 50176
#define NR_ (NROI_ * POOL_)             // 3584 output rows
#define NBINS_ 128                       // one bin per source row y0
#define CHUNKJ_ (NPIX_ / 8)              // 6272 jobs per XCD (= 448 rows * 14)

typedef float f32x4 __attribute__((ext_vector_type(4)));

// Source row y0 for output row rid = n*14 + yj.
__device__ __forceinline__ int row_y0(const float* __restrict__ rois, int rid) {
    const int n  = rid / POOL_;
    const int yj = rid % POOL_;
    const float y = rois[n * 4 + 1];
    const float h = rois[n * 4 + 3];
    const int c  = (int)rintf((y - h * 0.5f) / 16.0f);
    const int hf = max((int)rintf(h / 16.0f), 1);
    const float scy  = (float)hf / (float)POOL_;
    const float srcy = ((float)yj + 0.5f) * scy - 0.5f;
    const float fly  = floorf(srcy);
    int y0 = (int)fminf(fmaxf(fly, 0.0f), (float)(hf - 1)) + c;
    return min(max(y0, 0), H_ - 1);
}

// Single-block counting sort of 3584 rows by y0 (hist -> scan -> scatter).
// Intra-bin order is atomic-raced: irrelevant for locality, and d_out stays
// deterministic (each job writes its own disjoint 4KB).
__global__ __launch_bounds__(256) void sort_rows(
    const float* __restrict__ rois, int* __restrict__ ws)
{
    __shared__ int hist[NBINS_];
    __shared__ int off[NBINS_];
    const int tid = threadIdx.x;
    if (tid < NBINS_) hist[tid] = 0;
    __syncthreads();
    #pragma unroll
    for (int rid = tid; rid < NR_; rid += 256)
        atomicAdd(&hist[row_y0(rois, rid)], 1);
    __syncthreads();
    if (tid == 0) {
        int run = 0;
        for (int i = 0; i < NBINS_; ++i) { off[i] = run; run += hist[i]; }
    }
    __syncthreads();
    #pragma unroll
    for (int rid = tid; rid < NR_; rid += 256) {
        const int b = row_y0(rois, rid);
        const int pos = atomicAdd(&off[b], 1);
        ws[pos] = rid;
    }
}

// Main: job q (y0-sorted order) = (blockIdx%8)*CHUNKJ_ + blockIdx/8;
// row = ws[q/14], xj = q%14. XCD k streams ~16 image rows monotonically.
__global__ __launch_bounds__(256) void roi_pool_sorted(
    const float* __restrict__ feat, const float* __restrict__ rois,
    float* __restrict__ out, const int* __restrict__ ws)
{
    const int q   = (blockIdx.x & 7) * CHUNKJ_ + (blockIdx.x >> 3);
    const int rq  = q / POOL_;
    const int xj  = q - rq * POOL_;
    const int rid = ws[rq];                    // wave-uniform scalar load
    const int yj  = rid % POOL_;
    const int n   = rid / POOL_;

    const float x = rois[n * 4 + 0];
    const float y = rois[n * 4 + 1];
    const float w = rois[n * 4 + 2];
    const float h = rois[n * 4 + 3];

    // jnp.round == round-half-to-even == rintf
    const int r_  = (int)rintf((x - w * 0.5f) / 16.0f);
    const int c_  = (int)rintf((y - h * 0.5f) / 16.0f);
    const int wf = max((int)rintf(w / 16.0f), 1);
    const int hf = max((int)rintf(h / 16.0f), 1);

    // y axis
    const float scy  = (float)hf / (float)POOL_;
    const float srcy = ((float)yj + 0.5f) * scy - 0.5f;
    const float fly  = floorf(srcy);
    const float ty   = srcy - fly;
    const float hiy  = (float)(hf - 1);
    int y0 = (int)fminf(fmaxf(fly, 0.0f), hiy) + c_;
    int y1 = (int)fminf(fmaxf(fly + 1.0f, 0.0f), hiy) + c_;
    y0 = min(max(y0, 0), H_ - 1);
    y1 = min(max(y1, 0), H_ - 1);

    // x axis
    const float scx  = (float)wf / (float)POOL_;
    const float srcx = ((float)xj + 0.5f) * scx - 0.5f;
    const float flx  = floorf(srcx);
    const float tx   = srcx - flx;
    const float hix  = (float)(wf - 1);
    int x0 = (int)fminf(fmaxf(flx, 0.0f), hix) + r_;
    int x1 = (int)fminf(fmaxf(flx + 1.0f, 0.0f), hix) + r_;
    x0 = min(max(x0, 0), W_ - 1);
    x1 = min(max(x1, 0), W_ - 1);

    const f32x4* __restrict__ p00 = (const f32x4*)(feat + ((size_t)y0 * W_ + x0) * C_);
    const f32x4* __restrict__ p01 = (const f32x4*)(feat + ((size_t)y0 * W_ + x1) * C_);
    const f32x4* __restrict__ p10 = (const f32x4*)(feat + ((size_t)y1 * W_ + x0) * C_);
    const f32x4* __restrict__ p11 = (const f32x4*)(feat + ((size_t)y1 * W_ + x1) * C_);
    f32x4* __restrict__ po =
        (f32x4*)(out + (((size_t)n * (POOL_ * POOL_)) + (size_t)yj * POOL_ + xj) * C_);

    const int tid = threadIdx.x;

    const f32x4 v00 = p00[tid];
    const f32x4 v01 = p01[tid];
    const f32x4 v10 = p10[tid];
    const f32x4 v11 = p11[tid];

    const float omty = 1.0f - ty;
    const float omtx = 1.0f - tx;

    // Match reference order: (v00*(1-ty) + v10*ty)*(1-tx) + (v01*(1-ty) + v11*ty)*tx
    f32x4 o = (v00 * omty + v10 * ty) * omtx + (v01 * omty + v11 * ty) * tx;

    __builtin_nontemporal_store(o, &po[tid]);
}

// Fallback (ws too small): R3's proven direct kernel + XCD swizzle.
__global__ __launch_bounds__(256) void roi_pool_direct(
    const float* __restrict__ feat, const float* __restrict__ rois,
    float* __restrict__ out)
{
    const int bid = blockIdx.x;
    const int blk = (bid % 8) * (NPIX_ / 8) + bid / 8;

    const int xj = blk % POOL_;
    const int yj = (blk / POOL_) % POOL_;
    const int n  = blk / (POOL_ * POOL_);

    const float x = rois[n * 4 + 0];
    const float y = rois[n * 4 + 1];
    const float w = rois[n * 4 + 2];
    const float h = rois[n * 4 + 3];

    const int r_  = (int)rintf((x - w * 0.5f) / 16.0f);
    const int c_  = (int)rintf((y - h * 0.5f) / 16.0f);
    const int wf = max((int)rintf(w / 16.0f), 1);
    const int hf = max((int)rintf(h / 16.0f), 1);

    const float scy  = (float)hf / (float)POOL_;
    const float srcy = ((float)yj + 0.5f) * scy - 0.5f;
    const float fly  = floorf(srcy);
    const float ty   = srcy - fly;
    const float hiy  = (float)(hf - 1);
    int y0 = (int)fminf(fmaxf(fly, 0.0f), hiy) + c_;
    int y1 = (int)fminf(fmaxf(fly + 1.0f, 0.0f), hiy) + c_;
    y0 = min(max(y0, 0), H_ - 1);
    y1 = min(max(y1, 0), H_ - 1);

    const float scx  = (float)wf / (float)POOL_;
    const float srcx = ((float)xj + 0.5f) * scx - 0.5f;
    const float flx  = floorf(srcx);
    const float tx   = srcx - flx;
    const float hix  = (float)(wf - 1);
    int x0 = (int)fminf(fmaxf(flx, 0.0f), hix) + r_;
    int x1 = (int)fminf(fmaxf(flx + 1.0f, 0.0f), hix) + r_;
    x0 = min(max(x0, 0), W_ - 1);
    x1 = min(max(x1, 0), W_ - 1);

    const f32x4* __restrict__ p00 = (const f32x4*)(feat + ((size_t)y0 * W_ + x0) * C_);
    const f32x4* __restrict__ p01 = (const f32x4*)(feat + ((size_t)y0 * W_ + x1) * C_);
    const f32x4* __restrict__ p10 = (const f32x4*)(feat + ((size_t)y1 * W_ + x0) * C_);
    const f32x4* __restrict__ p11 = (const f32x4*)(feat + ((size_t)y1 * W_ + x1) * C_);
    f32x4* __restrict__ po = (f32x4*)(out + (size_t)blk * C_);

    const int tid = threadIdx.x;
    const f32x4 v00 = p00[tid];
    const f32x4 v01 = p01[tid];
    const f32x4 v10 = p10[tid];
    const f32x4 v11 = p11[tid];

    const float omty = 1.0f - ty;
    const float omtx = 1.0f - tx;
    f32x4 o = (v00 * omty + v10 * ty) * omtx + (v01 * omty + v11 * ty) * tx;
    __builtin_nontemporal_store(o, &po[tid]);
}

extern "C" void kernel_launch(void* const* d_in, const int* in_sizes, int n_in,
                              void* d_out, int out_size, void* d_ws, size_t ws_size,
                              hipStream_t stream) {
    const float* feat = (const float*)d_in[0];   // (1,128,128,1024) f32
    const float* rois = (const float*)d_in[1];   // (256,4) f32
    float* out = (float*)d_out;                  // (1,256,14,14,1024) f32

    if (ws_size < (size_t)NR_ * sizeof(int)) {
        roi_pool_direct<<<NPIX_, 256, 0, stream>>>(feat, rois, out);
        return;
    }

    int* ws = (int*)d_ws;
    sort_rows<<<1, 256, 0, stream>>>(rois, ws);
    roi_pool_sorted<<<NPIX_, 256, 0, stream>>>(feat, rois, out, ws);
}

// Round 10
// 60.113 us; speedup vs baseline: 2.6060x; 1.0247x over previous
//
#include <hip/hip_runtime.h>

// RoI bilinear crop-and-resize (TF2 half-pixel-center resize semantics).
// image: (1, 128, 128, 1024) f32, rois: (256, 4) f32 [x, y, w, h]
// out:   (1, 256, 14, 14, 1024) f32
//
// R9: y0-sorted ROW blocks. Sort kernel (1 block) counting-sorts the 3584
// output rows by source row y0 AND writes a per-row geometry record
// {rid, y0, y1, ty, r_, scx, hix} at the sorted position (32B/row).
// Main kernel: 3584 blocks, one per sorted row, pinned to XCD by chunk
// (blockIdx%8); one uniform record load, then the 14 xj pixels in a loop:
// 4 taps x f32x4 lerp + NT store (56KB contiguous store stream per block,
// x-window sweep gives L1 reuse of shared source columns).

#define H_ 128
#define W_ 128
#define C_ 1024
#define POOL_ 14
#define NROI_ 256
#define NPIX_ (NROI_ * POOL_ * POOL_)   // 50176
#define NR_ (NROI_ * POOL_)             // 3584 output rows
#define NBINS_ 128                       // one bin per source row y0
#define CHUNKR_ (NR_ / 8)                // 448 rows per XCD
#define RECW_ 8                          // ints per row record
#define WS_INTS (NR_ * RECW_)            // 28672 ints = 114KB

typedef float f32x4 __attribute__((ext_vector_type(4)));

// Single-block: counting sort of 3584 rows by y0 + per-row geometry records.
__global__ __launch_bounds__(256) void sort_rows(
    const float* __restrict__ rois, int* __restrict__ ws)
{
    __shared__ int hist[NBINS_];
    __shared__ int off[NBINS_];
    const int tid = threadIdx.x;
    if (tid < NBINS_) hist[tid] = 0;
    __syncthreads();

    // Pass 1: histogram of y0 over rows.
    for (int rid = tid; rid < NR_; rid += 256) {
        const int n  = rid / POOL_;
        const int yj = rid % POOL_;
        const float y = rois[n * 4 + 1];
        const float h = rois[n * 4 + 3];
        const int c  = (int)rintf((y - h * 0.5f) / 16.0f);
        const int hf = max((int)rintf(h / 16.0f), 1);
        const float scy  = (float)hf / (float)POOL_;
        const float srcy = ((float)yj + 0.5f) * scy - 0.5f;
        const float fly  = floorf(srcy);
        int y0 = (int)fminf(fmaxf(fly, 0.0f), (float)(hf - 1)) + c;
        y0 = min(max(y0, 0), H_ - 1);
        atomicAdd(&hist[y0], 1);
    }
    __syncthreads();
    if (tid == 0) {
        int run = 0;
        for (int i = 0; i < NBINS_; ++i) { off[i] = run; run += hist[i]; }
    }
    __syncthreads();

    // Pass 2: scatter — full geometry record at sorted position.
    for (int rid = tid; rid < NR_; rid += 256) {
        const int n  = rid / POOL_;
        const int yj = rid % POOL_;
        const float x = rois[n * 4 + 0];
        const float y = rois[n * 4 + 1];
        const float w = rois[n * 4 + 2];
        const float h = rois[n * 4 + 3];

        const int r_  = (int)rintf((x - w * 0.5f) / 16.0f);
        const int c_  = (int)rintf((y - h * 0.5f) / 16.0f);
        const int wf = max((int)rintf(w / 16.0f), 1);
        const int hf = max((int)rintf(h / 16.0f), 1);

        const float scy  = (float)hf / (float)POOL_;
        const float srcy = ((float)yj + 0.5f) * scy - 0.5f;
        const float fly  = floorf(srcy);
        const float ty   = srcy - fly;
        const float hiy  = (float)(hf - 1);
        int y0 = (int)fminf(fmaxf(fly, 0.0f), hiy) + c_;
        int y1 = (int)fminf(fmaxf(fly + 1.0f, 0.0f), hiy) + c_;
        y0 = min(max(y0, 0), H_ - 1);
        y1 = min(max(y1, 0), H_ - 1);

        const int pos = atomicAdd(&off[y0], 1);   // intra-bin order irrelevant
        int* rec = ws + pos * RECW_;
        rec[0] = rid;
        rec[1] = y0;
        rec[2] = y1;
        ((float*)rec)[3] = ty;
        rec[4] = r_;
        ((float*)rec)[5] = (float)wf / (float)POOL_;  // scx
        ((float*)rec)[6] = (float)(wf - 1);           // hix
        rec[7] = 0;
    }
}

// Main: one block per sorted row; XCD k gets rows [k*448,(k+1)*448).
__global__ __launch_bounds__(256) void roi_pool_rows(
    const float* __restrict__ feat, float* __restrict__ out,
    const int* __restrict__ ws)
{
    const int pos = (blockIdx.x & 7) * CHUNKR_ + (blockIdx.x >> 3);
    const int* rec = ws + pos * RECW_;
    const int   rid = rec[0];
    const int   y0  = rec[1];
    const int   y1  = rec[2];
    const float ty  = ((const float*)rec)[3];
    const int   r_  = rec[4];
    const float scx = ((const float*)rec)[5];
    const float hix = ((const float*)rec)[6];

    const int n  = rid / POOL_;
    const int yj = rid % POOL_;

    const float* __restrict__ row0 = feat + (size_t)y0 * (W_ * C_);
    const float* __restrict__ row1 = feat + (size_t)y1 * (W_ * C_);
    float* __restrict__ orow =
        out + ((size_t)n * (POOL_ * POOL_) + (size_t)yj * POOL_) * C_;

    const int tid = threadIdx.x;          // channel group, f32x4
    const float omty = 1.0f - ty;

    #pragma unroll 2
    for (int xj = 0; xj < POOL_; ++xj) {
        const float srcx = ((float)xj + 0.5f) * scx - 0.5f;
        const float flx  = floorf(srcx);
        const float tx   = srcx - flx;
        int x0 = (int)fminf(fmaxf(flx, 0.0f), hix) + r_;
        int x1 = (int)fminf(fmaxf(flx + 1.0f, 0.0f), hix) + r_;
        x0 = min(max(x0, 0), W_ - 1);
        x1 = min(max(x1, 0), W_ - 1);

        const f32x4 v00 = ((const f32x4*)(row0 + (size_t)x0 * C_))[tid];
        const f32x4 v01 = ((const f32x4*)(row0 + (size_t)x1 * C_))[tid];
        const f32x4 v10 = ((const f32x4*)(row1 + (size_t)x0 * C_))[tid];
        const f32x4 v11 = ((const f32x4*)(row1 + (size_t)x1 * C_))[tid];

        const float omtx = 1.0f - tx;
        // Match reference order:
        // (v00*(1-ty) + v10*ty)*(1-tx) + (v01*(1-ty) + v11*ty)*tx
        f32x4 o = (v00 * omty + v10 * ty) * omtx + (v01 * omty + v11 * ty) * tx;

        __builtin_nontemporal_store(o, (f32x4*)(orow + (size_t)xj * C_) + tid);
    }
}

// Fallback (ws too small): R3's proven direct kernel + XCD swizzle.
__global__ __launch_bounds__(256) void roi_pool_direct(
    const float* __restrict__ feat, const float* __restrict__ rois,
    float* __restrict__ out)
{
    const int bid = blockIdx.x;
    const int blk = (bid % 8) * (NPIX_ / 8) + bid / 8;

    const int xj = blk % POOL_;
    const int yj = (blk / POOL_) % POOL_;
    const int n  = blk / (POOL_ * POOL_);

    const float x = rois[n * 4 + 0];
    const float y = rois[n * 4 + 1];
    const float w = rois[n * 4 + 2];
    const float h = rois[n * 4 + 3];

    const int r_  = (int)rintf((x - w * 0.5f) / 16.0f);
    const int c_  = (int)rintf((y - h * 0.5f) / 16.0f);
    const int wf = max((int)rintf(w / 16.0f), 1);
    const int hf = max((int)rintf(h / 16.0f), 1);

    const float scy  = (float)hf / (float)POOL_;
    const float srcy = ((float)yj + 0.5f) * scy - 0.5f;
    const float fly  = floorf(srcy);
    const float ty   = srcy - fly;
    const float hiy  = (float)(hf - 1);
    int y0 = (int)fminf(fmaxf(fly, 0.0f), hiy) + c_;
    int y1 = (int)fminf(fmaxf(fly + 1.0f, 0.0f), hiy) + c_;
    y0 = min(max(y0, 0), H_ - 1);
    y1 = min(max(y1, 0), H_ - 1);

    const float scx  = (float)wf / (float)POOL_;
    const float srcx = ((float)xj + 0.5f) * scx - 0.5f;
    const float flx  = floorf(srcx);
    const float tx   = srcx - flx;
    const float hix  = (float)(wf - 1);
    int x0 = (int)fminf(fmaxf(flx, 0.0f), hix) + r_;
    int x1 = (int)fminf(fmaxf(flx + 1.0f, 0.0f), hix) + r_;
    x0 = min(max(x0, 0), W_ - 1);
    x1 = min(max(x1, 0), W_ - 1);

    const f32x4* __restrict__ p00 = (const f32x4*)(feat + ((size_t)y0 * W_ + x0) * C_);
    const f32x4* __restrict__ p01 = (const f32x4*)(feat + ((size_t)y0 * W_ + x1) * C_);
    const f32x4* __restrict__ p10 = (const f32x4*)(feat + ((size_t)y1 * W_ + x0) * C_);
    const f32x4* __restrict__ p11 = (const f32x4*)(feat + ((size_t)y1 * W_ + x1) * C_);
    f32x4* __restrict__ po = (f32x4*)(out + (size_t)blk * C_);

    const int tid = threadIdx.x;
    const f32x4 v00 = p00[tid];
    const f32x4 v01 = p01[tid];
    const f32x4 v10 = p10[tid];
    const f32x4 v11 = p11[tid];

    const float omty = 1.0f - ty;
    const float omtx = 1.0f - tx;
    f32x4 o = (v00 * omty + v10 * ty) * omtx + (v01 * omty + v11 * ty) * tx;
    __builtin_nontemporal_store(o, &po[tid]);
}

extern "C" void kernel_launch(void* const* d_in, const int* in_sizes, int n_in,
                              void* d_out, int out_size, void* d_ws, size_t ws_size,
                              hipStream_t stream) {
    const float* feat = (const float*)d_in[0];   // (1,128,128,1024) f32
    const float* rois = (const float*)d_in[1];   // (256,4) f32
    float* out = (float*)d_out;                  // (1,256,14,14,1024) f32

    if (ws_size < (size_t)WS_INTS * sizeof(int)) {
        roi_pool_direct<<<NPIX_, 256, 0, stream>>>(feat, rois, out);
        return;
    }

    int* ws = (int*)d_ws;
    sort_rows<<<1, 256, 0, stream>>>(rois, ws);
    roi_pool_rows<<<NR_, 256, 0, stream>>>(feat, out, ws);
}

// Round 11
// 56.301 us; speedup vs baseline: 2.7825x; 1.0677x over previous
//
#include <hip/hip_runtime.h>

// RoI bilinear crop-and-resize (TF2 half-pixel-center resize semantics).
// image: (1, 128, 128, 1024) f32, rois: (256, 4) f32 [x, y, w, h]
// out:   (1, 256, 14, 14, 1024) f32
//
// R11: R10 (y0-sorted row blocks + per-row geometry records + NT stores +
// XCD chunking) with: sort kernel widened to 1024 threads (shrink the serial
// 1-CU prologue), and the main xj loop unrolled 4x for deeper load
// pipelining (16 loads in flight between dependent NT stores).

#define H_ 128
#define W_ 128
#define C_ 1024
#define POOL_ 14
#define NROI_ 256
#define NPIX_ (NROI_ * POOL_ * POOL_)   // 50176
#define NR_ (NROI_ * POOL_)             // 3584 output rows
#define NBINS_ 128                       // one bin per source row y0
#define CHUNKR_ (NR_ / 8)                // 448 rows per XCD
#define RECW_ 8                          // ints per row record
#define WS_INTS (NR_ * RECW_)            // 28672 ints = 114KB

typedef float f32x4 __attribute__((ext_vector_type(4)));

// Single-block (1024 thr): counting sort of 3584 rows by y0 + geometry records.
__global__ __launch_bounds__(1024) void sort_rows(
    const float* __restrict__ rois, int* __restrict__ ws)
{
    __shared__ int hist[NBINS_];
    __shared__ int off[NBINS_];
    const int tid = threadIdx.x;
    if (tid < NBINS_) hist[tid] = 0;
    __syncthreads();

    // Pass 1: histogram of y0 over rows.
    for (int rid = tid; rid < NR_; rid += 1024) {
        const int n  = rid / POOL_;
        const int yj = rid % POOL_;
        const float y = rois[n * 4 + 1];
        const float h = rois[n * 4 + 3];
        const int c  = (int)rintf((y - h * 0.5f) / 16.0f);
        const int hf = max((int)rintf(h / 16.0f), 1);
        const float scy  = (float)hf / (float)POOL_;
        const float srcy = ((float)yj + 0.5f) * scy - 0.5f;
        const float fly  = floorf(srcy);
        int y0 = (int)fminf(fmaxf(fly, 0.0f), (float)(hf - 1)) + c;
        y0 = min(max(y0, 0), H_ - 1);
        atomicAdd(&hist[y0], 1);
    }
    __syncthreads();
    if (tid == 0) {
        int run = 0;
        for (int i = 0; i < NBINS_; ++i) { off[i] = run; run += hist[i]; }
    }
    __syncthreads();

    // Pass 2: scatter — full geometry record at sorted position.
    for (int rid = tid; rid < NR_; rid += 1024) {
        const int n  = rid / POOL_;
        const int yj = rid % POOL_;
        const float x = rois[n * 4 + 0];
        const float y = rois[n * 4 + 1];
        const float w = rois[n * 4 + 2];
        const float h = rois[n * 4 + 3];

        const int r_  = (int)rintf((x - w * 0.5f) / 16.0f);
        const int c_  = (int)rintf((y - h * 0.5f) / 16.0f);
        const int wf = max((int)rintf(w / 16.0f), 1);
        const int hf = max((int)rintf(h / 16.0f), 1);

        const float scy  = (float)hf / (float)POOL_;
        const float srcy = ((float)yj + 0.5f) * scy - 0.5f;
        const float fly  = floorf(srcy);
        const float ty   = srcy - fly;
        const float hiy  = (float)(hf - 1);
        int y0 = (int)fminf(fmaxf(fly, 0.0f), hiy) + c_;
        int y1 = (int)fminf(fmaxf(fly + 1.0f, 0.0f), hiy) + c_;
        y0 = min(max(y0, 0), H_ - 1);
        y1 = min(max(y1, 0), H_ - 1);

        const int pos = atomicAdd(&off[y0], 1);   // intra-bin order irrelevant
        int* rec = ws + pos * RECW_;
        rec[0] = rid;
        rec[1] = y0;
        rec[2] = y1;
        ((float*)rec)[3] = ty;
        rec[4] = r_;
        ((float*)rec)[5] = (float)wf / (float)POOL_;  // scx
        ((float*)rec)[6] = (float)(wf - 1);           // hix
        rec[7] = 0;
    }
}

// Main: one block per sorted row; XCD k gets rows [k*448,(k+1)*448).
__global__ __launch_bounds__(256) void roi_pool_rows(
    const float* __restrict__ feat, float* __restrict__ out,
    const int* __restrict__ ws)
{
    const int pos = (blockIdx.x & 7) * CHUNKR_ + (blockIdx.x >> 3);
    const int* rec = ws + pos * RECW_;
    const int   rid = rec[0];
    const int   y0  = rec[1];
    const int   y1  = rec[2];
    const float ty  = ((const float*)rec)[3];
    const int   r_  = rec[4];
    const float scx = ((const float*)rec)[5];
    const float hix = ((const float*)rec)[6];

    const int n  = rid / POOL_;
    const int yj = rid % POOL_;

    const float* __restrict__ row0 = feat + (size_t)y0 * (W_ * C_);
    const float* __restrict__ row1 = feat + (size_t)y1 * (W_ * C_);
    float* __restrict__ orow =
        out + ((size_t)n * (POOL_ * POOL_) + (size_t)yj * POOL_) * C_;

    const int tid = threadIdx.x;          // channel group, f32x4
    const float omty = 1.0f - ty;

    #pragma unroll 4
    for (int xj = 0; xj < POOL_; ++xj) {
        const float srcx = ((float)xj + 0.5f) * scx - 0.5f;
        const float flx  = floorf(srcx);
        const float tx   = srcx - flx;
        int x0 = (int)fminf(fmaxf(flx, 0.0f), hix) + r_;
        int x1 = (int)fminf(fmaxf(flx + 1.0f, 0.0f), hix) + r_;
        x0 = min(max(x0, 0), W_ - 1);
        x1 = min(max(x1, 0), W_ - 1);

        const f32x4 v00 = ((const f32x4*)(row0 + (size_t)x0 * C_))[tid];
        const f32x4 v01 = ((const f32x4*)(row0 + (size_t)x1 * C_))[tid];
        const f32x4 v10 = ((const f32x4*)(row1 + (size_t)x0 * C_))[tid];
        const f32x4 v11 = ((const f32x4*)(row1 + (size_t)x1 * C_))[tid];

        const float omtx = 1.0f - tx;
        // Match reference order:
        // (v00*(1-ty) + v10*ty)*(1-tx) + (v01*(1-ty) + v11*ty)*tx
        f32x4 o = (v00 * omty + v10 * ty) * omtx + (v01 * omty + v11 * ty) * tx;

        __builtin_nontemporal_store(o, (f32x4*)(orow + (size_t)xj * C_) + tid);
    }
}

// Fallback (ws too small): R3's proven direct kernel + XCD swizzle.
__global__ __launch_bounds__(256) void roi_pool_direct(
    const float* __restrict__ feat, const float* __restrict__ rois,
    float* __restrict__ out)
{
    const int bid = blockIdx.x;
    const int blk = (bid % 8) * (NPIX_ / 8) + bid / 8;

    const int xj = blk % POOL_;
    const int yj = (blk / POOL_) % POOL_;
    const int n  = blk / (POOL_ * POOL_);

    const float x = rois[n * 4 + 0];
    const float y = rois[n * 4 + 1];
    const float w = rois[n * 4 + 2];
    const float h = rois[n * 4 + 3];

    const int r_  = (int)rintf((x - w * 0.5f) / 16.0f);
    const int c_  = (int)rintf((y - h * 0.5f) / 16.0f);
    const int wf = max((int)rintf(w / 16.0f), 1);
    const int hf = max((int)rintf(h / 16.0f), 1);

    const float scy  = (float)hf / (float)POOL_;
    const float srcy = ((float)yj + 0.5f) * scy - 0.5f;
    const float fly  = floorf(srcy);
    const float ty   = srcy - fly;
    const float hiy  = (float)(hf - 1);
    int y0 = (int)fminf(fmaxf(fly, 0.0f), hiy) + c_;
    int y1 = (int)fminf(fmaxf(fly + 1.0f, 0.0f), hiy) + c_;
    y0 = min(max(y0, 0), H_ - 1);
    y1 = min(max(y1, 0), H_ - 1);

    const float scx  = (float)wf / (float)POOL_;
    const float srcx = ((float)xj + 0.5f) * scx - 0.5f;
    const float flx  = floorf(srcx);
    const float tx   = srcx - flx;
    const float hix  = (float)(wf - 1);
    int x0 = (int)fminf(fmaxf(flx, 0.0f), hix) + r_;
    int x1 = (int)fminf(fmaxf(flx + 1.0f, 0.0f), hix) + r_;
    x0 = min(max(x0, 0), W_ - 1);
    x1 = min(max(x1, 0), W_ - 1);

    const f32x4* __restrict__ p00 = (const f32x4*)(feat + ((size_t)y0 * W_ + x0) * C_);
    const f32x4* __restrict__ p01 = (const f32x4*)(feat + ((size_t)y0 * W_ + x1) * C_);
    const f32x4* __restrict__ p10 = (const f32x4*)(feat + ((size_t)y1 * W_ + x0) * C_);
    const f32x4* __restrict__ p11 = (const f32x4*)(feat + ((size_t)y1 * W_ + x1) * C_);
    f32x4* __restrict__ po = (f32x4*)(out + (size_t)blk * C_);

    const int tid = threadIdx.x;
    const f32x4 v00 = p00[tid];
    const f32x4 v01 = p01[tid];
    const f32x4 v10 = p10[tid];
    const f32x4 v11 = p11[tid];

    const float omty = 1.0f - ty;
    const float omtx = 1.0f - tx;
    f32x4 o = (v00 * omty + v10 * ty) * omtx + (v01 * omty + v11 * ty) * tx;
    __builtin_nontemporal_store(o, &po[tid]);
}

extern "C" void kernel_launch(void* const* d_in, const int* in_sizes, int n_in,
                              void* d_out, int out_size, void* d_ws, size_t ws_size,
                              hipStream_t stream) {
    const float* feat = (const float*)d_in[0];   // (1,128,128,1024) f32
    const float* rois = (const float*)d_in[1];   // (256,4) f32
    float* out = (float*)d_out;                  // (1,256,14,14,1024) f32

    if (ws_size < (size_t)WS_INTS * sizeof(int)) {
        roi_pool_direct<<<NPIX_, 256, 0, stream>>>(feat, rois, out);
        return;
    }

    int* ws = (int*)d_ws;
    sort_rows<<<1, 1024, 0, stream>>>(rois, ws);
    roi_pool_rows<<<NR_, 256, 0, stream>>>(feat, out, ws);
}